// Round 11
// baseline (881.404 us; speedup 1.0000x reference)
//
#include <hip/hip_runtime.h>

#define T 1024
#define BATCH 512
#define EMB 64
#define HID 64
#define NGATE 256
#define VOCABP1 50001

typedef unsigned int uint32;
typedef unsigned short u16;
typedef __attribute__((ext_vector_type(8))) short short8;   // 8 bf16 = 4 VGPRs
typedef __attribute__((ext_vector_type(4))) float f32x4;    // MFMA C/D

__device__ __forceinline__ float rcpf(float x) { return __builtin_amdgcn_rcpf(x); }
__device__ __forceinline__ float sigm(float x) { return rcpf(1.0f + __expf(-x)); }
__device__ __forceinline__ float tanhfast(float x) { return 1.0f - 2.0f * rcpf(__expf(2.0f * x) + 1.0f); }
__device__ __forceinline__ u16 f2bf(float x) {        // RNE f32->bf16
    uint32 u = __float_as_uint(x);
    u += 0x7fffu + ((u >> 16) & 1u);
    return (u16)(u >> 16);
}
__device__ __forceinline__ float bf2f(u16 h) { return __uint_as_float(((uint32)h) << 16); }

// LDS-only barrier: drains lgkmcnt but leaves global loads in flight.
#define BARRIER_LDS() asm volatile("s_waitcnt lgkmcnt(0)\n\ts_barrier" ::: "memory")
#define WAIT_LDS()    asm volatile("s_waitcnt lgkmcnt(0)" ::: "memory")

// ---------------------------------------------------------------------------
// bf16 cast of the embedding table.
// ---------------------------------------------------------------------------
__global__ void embbf_kernel(const float* __restrict__ emb, u16* __restrict__ embbf)
{
    const int i = blockIdx.x * 256 + threadIdx.x;
    if (i < VOCABP1 * EMB) embbf[i] = f2bf(emb[i]);
}

// ---------------------------------------------------------------------------
// Mask bit-words: mbits[d][b][w] bit i = (x_step(d,b,w*32+i) != 0)
// ---------------------------------------------------------------------------
__global__ void maskprep_kernel(const int* __restrict__ x, uint32* __restrict__ mbits)
{
    const int idx  = blockIdx.x * 256 + threadIdx.x;
    const int word = idx & 31;
    const int db   = idx >> 5;
    const int d    = db >> 9;
    const int b    = db & 511;
    const int* src = x + b * T;
    uint32 m = 0;
#pragma unroll 8
    for (int i = 0; i < 32; ++i) {
        const int t = word * 32 + i;
        m |= (src[d ? (T - 1 - t) : t] != 0 ? 1u : 0u) << i;
    }
    mbits[idx] = m;
}

// ---------------------------------------------------------------------------
// A-fragment emb stream (one stream serves both directions).
// ---------------------------------------------------------------------------
__global__ void xstream_kernel(const int* __restrict__ x,
                               const u16* __restrict__ embbf,
                               u16* __restrict__ xstream)
{
    const int gb    = blockIdx.x >> 6;
    const int stile = blockIdx.x & 63;
    const int tid   = threadIdx.x;
    const int lane  = tid & 63;
    const int half  = tid >> 6;
    const int ks    = half & 1;
    const int sp    = half >> 1;
    const int m     = lane & 15;
    const int qj    = (lane >> 4) * 8;
#pragma unroll
    for (int i = 0; i < 8; ++i) {
        const int s   = stile * 16 + sp * 8 + i;
        const int tok = x[(gb * 16 + m) * T + s];
        const short8 v = *(const short8*)(embbf + (size_t)tok * EMB + ks * 32 + qj);
        *(short8*)(xstream + ((size_t)(gb * 1024 + s) * 128 + ks * 64 + lane) * 8) = v;
    }
}

// ---------------------------------------------------------------------------
// B-fragment prep, GATE-INTERLEAVED v2: wave w owns units [8w,8w+8), tiles
// t=0,1 cover (4 gates x 4 units): col(n) = (n>>2)*64 + 8w + 4t + (n&3).
//   idx = (((dw*2+t)*2+ks)*3+var)*512 + lane*8 + j,  k = ks*32+(lane>>4)*8+j
//   var: 0=U-hi, 1=U-lo, 2=W-hi
// ---------------------------------------------------------------------------
__global__ void bfrag_kernel(const float* __restrict__ Uf, const float* __restrict__ Ub,
                             const float* __restrict__ Wf, const float* __restrict__ Wb,
                             u16* __restrict__ bfrag)
{
    const int dw = blockIdx.x;                 // d*8 + w
    const int d  = dw >> 3, w = dw & 7;
    const float* U = d ? Ub : Uf;
    const float* W = d ? Wb : Wf;
    const int tid = threadIdx.x, lane = tid & 63, sub = tid >> 6;
    const int t = sub >> 1, ks = sub & 1;
    const int n = lane & 15, g = n >> 2, su = n & 3;
    const int col = g * 64 + 8 * w + 4 * t + su;
#pragma unroll
    for (int j = 0; j < 8; ++j) {
        const int k = ks * 32 + (lane >> 4) * 8 + j;
        const float uv = U[k * NGATE + col];
        const u16 uhi = f2bf(uv);
        const u16 ulo = f2bf(uv - bf2f(uhi));
        const u16 whi = f2bf(W[k * NGATE + col]);
        const size_t base = (((size_t)dw * 2 + t) * 2 + ks) * 3;
        bfrag[(base + 0) * 512 + lane * 8 + j] = uhi;
        bfrag[(base + 1) * 512 + lane * 8 + j] = ulo;
        bfrag[(base + 2) * 512 + lane * 8 + j] = whi;
    }
}

// ---------------------------------------------------------------------------
// MFMA LSTM v2: 64 blocks x 512 threads (8 waves = 2/SIMD for pipe overlap).
// R10 analysis: active-CU MfmaUtil ~30% + VALUBusy ~56% -> phases serialize
// at 1 wave/SIMD. v2: wave owns all 4 gates for 8 units (gate-interleaved B)
// -> 16 MFMA + half epilogue per wave; gate exchange is WITHIN-wave (private
// LDS scratch + lgkmcnt, no barrier); one block barrier/step for h-frags.
// Two waves/SIMD co-issue MFMA and VALU (m114) -> step ~= max(pipes).
// ---------------------------------------------------------------------------
__global__ __launch_bounds__(512, 1)
void lstm_mfma(const uint32* __restrict__ mbits,
               const u16* __restrict__ xstream,
               const u16* __restrict__ bfragp,
               const float* __restrict__ bf, const float* __restrict__ bb,
               float* __restrict__ hcat)
{
    const int tid  = threadIdx.x;
    const int lane = tid & 63;
    const int w    = tid >> 6;          // wave 0..7: units [8w, 8w+8)
    const int d    = blockIdx.x >> 5;
    const int gb   = blockIdx.x & 31;

    // MFMA-column identity: n = lane&15 -> (gate, su); C row = quad*4+r = m
    const int su   = lane & 3;
    // epilogue identity: (unit, m) pairs
    const int ul7  = lane & 7;          // unit = 8w + ul7
    const int q    = lane >> 3;         // m = 2q+p
    const int tsrc = (lane >> 2) & 1;   // tile holding this unit's columns
    const int ksh  = w >> 2;            // h-frag K-section this wave writes
    const int rowb = (w & 3) * 16;      // h-frag row base

    // B fragments (AGPR-friendly)
    short8 BU[2][2][2];   // [t][ks][hi/lo]
    short8 BW[2][2];      // [t][ks]
    {
        const u16* pb = bfragp + (size_t)(d * 8 + w) * 2 * 2 * 3 * 512;
#pragma unroll
        for (int t = 0; t < 2; ++t)
#pragma unroll
        for (int ks = 0; ks < 2; ++ks) {
            const size_t b0 = ((size_t)(t * 2 + ks) * 3) * 512 + lane * 8;
            BU[t][ks][0] = *(const short8*)&pb[b0];
            BU[t][ks][1] = *(const short8*)&pb[b0 + 512];
            BW[t][ks]    = *(const short8*)&pb[b0 + 1024];
        }
    }
    float biasv[2];
    {
        const float* bias = d ? bb : bf;
        const int g = (lane & 15) >> 2;
#pragma unroll
        for (int t = 0; t < 2; ++t) biasv[t] = bias[g * 64 + 8 * w + 4 * t + su];
    }

    __shared__ u16 Ahi[2][2][64][8];       // [buf][ks][row][j]
    __shared__ u16 Alo[2][2][64][8];
    __shared__ float scr[8][8][64];        // per-wave gate scratch [w][t*4+r][lane]
    {
        u16* f = &Ahi[0][0][0][0];
        for (int i = tid; i < 2 * 2 * 64 * 8; i += 512) f[i] = 0;
        u16* f2 = &Alo[0][0][0][0];
        for (int i = tid; i < 2 * 2 * 64 * 8; i += 512) f2[i] = 0;
    }

    // mask streams for rows m=2q and m=2q+1
    const uint32* mr0 = mbits + (size_t)(d * 512 + gb * 16 + 2 * q) * 32;
    const uint32* mr1 = mr0 + 32;
    uint32 mcur0 = mr0[0], mnext0 = mr0[1];
    uint32 mcur1 = mr1[0], mnext1 = mr1[1];

    const u16* sptr = xstream + (size_t)gb * 1024 * 1024;
    short8 axr[2][2];
    {
        const int c0 = d ? 1023 : 0;
        const int c1 = d ? 1022 : 1;
        axr[0][0] = *(const short8*)(sptr + (size_t)c0 * 1024 + lane * 8);
        axr[0][1] = *(const short8*)(sptr + (size_t)c0 * 1024 + 512 + lane * 8);
        axr[1][0] = *(const short8*)(sptr + (size_t)c1 * 1024 + lane * 8);
        axr[1][1] = *(const short8*)(sptr + (size_t)c1 * 1024 + 512 + lane * 8);
    }
    __syncthreads();

    float hv[2] = {0.f, 0.f};
    float cv[2] = {0.f, 0.f};

#define STEP(SV, P, PREF)                                                      \
  {                                                                            \
    /* x-part: register-only, before barrier */                                \
    f32x4 acc0, acc1;                                                          \
    acc0[0] = biasv[0]; acc0[1] = biasv[0]; acc0[2] = biasv[0]; acc0[3] = biasv[0]; \
    acc1[0] = biasv[1]; acc1[1] = biasv[1]; acc1[2] = biasv[1]; acc1[3] = biasv[1]; \
    acc0 = __builtin_amdgcn_mfma_f32_16x16x32_bf16(axr[P][0], BW[0][0], acc0, 0, 0, 0); \
    acc0 = __builtin_amdgcn_mfma_f32_16x16x32_bf16(axr[P][1], BW[0][1], acc0, 0, 0, 0); \
    acc1 = __builtin_amdgcn_mfma_f32_16x16x32_bf16(axr[P][0], BW[1][0], acc1, 0, 0, 0); \
    acc1 = __builtin_amdgcn_mfma_f32_16x16x32_bf16(axr[P][1], BW[1][1], acc1, 0, 0, 0); \
    /* stream ring refill for step SV+2 */                                     \
    {                                                                          \
      const int cs = ((SV) + 2 <= 1023) ? ((SV) + 2) : 1023;                   \
      const int c2 = d ? (1023 - cs) : cs;                                     \
      const u16* cp = sptr + (size_t)c2 * 1024;                                \
      axr[P][0] = *(const short8*)(cp + lane * 8);                             \
      axr[P][1] = *(const short8*)(cp + 512 + lane * 8);                       \
    }                                                                          \
    if ((PREF) && (((SV) & 31) == 0) && ((SV) > 0)) {                          \
      const int wn = ((SV) >> 5) + 1;                                          \
      const int wc = (wn < 32) ? wn : 31;                                      \
      mcur0 = mnext0; mnext0 = mr0[wc];                                        \
      mcur1 = mnext1; mnext1 = mr1[wc];                                        \
    }                                                                          \
    BARRIER_LDS();                                                             \
    const short8 Ah0 = *(const short8*)&Ahi[1 - (P)][0][lane][0];              \
    const short8 Ah1 = *(const short8*)&Ahi[1 - (P)][1][lane][0];              \
    const short8 Al0 = *(const short8*)&Alo[1 - (P)][0][lane][0];              \
    const short8 Al1 = *(const short8*)&Alo[1 - (P)][1][lane][0];              \
    acc0 = __builtin_amdgcn_mfma_f32_16x16x32_bf16(Ah0, BU[0][0][0], acc0, 0, 0, 0); \
    acc0 = __builtin_amdgcn_mfma_f32_16x16x32_bf16(Ah1, BU[0][1][0], acc0, 0, 0, 0); \
    acc0 = __builtin_amdgcn_mfma_f32_16x16x32_bf16(Ah0, BU[0][0][1], acc0, 0, 0, 0); \
    acc0 = __builtin_amdgcn_mfma_f32_16x16x32_bf16(Ah1, BU[0][1][1], acc0, 0, 0, 0); \
    acc0 = __builtin_amdgcn_mfma_f32_16x16x32_bf16(Al0, BU[0][0][0], acc0, 0, 0, 0); \
    acc0 = __builtin_amdgcn_mfma_f32_16x16x32_bf16(Al1, BU[0][1][0], acc0, 0, 0, 0); \
    acc1 = __builtin_amdgcn_mfma_f32_16x16x32_bf16(Ah0, BU[1][0][0], acc1, 0, 0, 0); \
    acc1 = __builtin_amdgcn_mfma_f32_16x16x32_bf16(Ah1, BU[1][1][0], acc1, 0, 0, 0); \
    acc1 = __builtin_amdgcn_mfma_f32_16x16x32_bf16(Ah0, BU[1][0][1], acc1, 0, 0, 0); \
    acc1 = __builtin_amdgcn_mfma_f32_16x16x32_bf16(Ah1, BU[1][1][1], acc1, 0, 0, 0); \
    acc1 = __builtin_amdgcn_mfma_f32_16x16x32_bf16(Al0, BU[1][0][0], acc1, 0, 0, 0); \
    acc1 = __builtin_amdgcn_mfma_f32_16x16x32_bf16(Al1, BU[1][1][0], acc1, 0, 0, 0); \
    /* within-wave gate exchange: no barrier, lgkm only */                     \
    _Pragma("unroll")                                                          \
    for (int r = 0; r < 4; ++r) { scr[w][r][lane] = acc0[r];                   \
                                  scr[w][4 + r][lane] = acc1[r]; }             \
    WAIT_LDS();                                                                \
    _Pragma("unroll")                                                          \
    for (int p = 0; p < 2; ++p) {                                              \
      const int mrow = tsrc * 4 + 2 * (q & 1) + p;                             \
      const int lsb  = (q >> 1) * 16 + su;                                     \
      const float ig = scr[w][mrow][lsb];                                      \
      const float fg = scr[w][mrow][lsb + 4];                                  \
      const float gg = scr[w][mrow][lsb + 8];                                  \
      const float og = scr[w][mrow][lsb + 12];                                 \
      const float iv = sigm(ig);                                               \
      const float fv = sigm(fg);                                               \
      const float gv = tanhfast(gg);                                           \
      const float ov = sigm(og);                                               \
      const float cn = fmaf(fv, cv[p], iv * gv);                               \
      const float hn = ov * tanhfast(cn);                                      \
      const uint32 mbit = ((p ? mcur1 : mcur0) >> ((SV) & 31)) & 1u;           \
      if (mbit) { cv[p] = cn; hv[p] = hn; }                                    \
      const uint32 uh = __float_as_uint(hv[p]);                                \
      const u16 hhi = (u16)(uh >> 16);                                         \
      const u16 hlo = f2bf(hv[p] - bf2f(hhi));                                 \
      Ahi[(P)][ksh][rowb + 2 * q + p][ul7] = hhi;                              \
      Alo[(P)][ksh][rowb + 2 * q + p][ul7] = hlo;                              \
    }                                                                          \
  }

    for (int s = 0; s < T; s += 2) {
        STEP(s, 0, 1)
        STEP(s + 1, 1, 0)
    }
#undef STEP

#pragma unroll
    for (int p = 0; p < 2; ++p)
        hcat[(size_t)(gb * 16 + 2 * q + p) * (2 * HID) + d * HID + 8 * w + ul7] = hv[p];
}

// ---------------------------------------------------------------------------
// Tiny MLP head: out[b] = relu(hcat[b] @ W1 + b1) @ W2 + b2
// ---------------------------------------------------------------------------
__global__ void mlp_kernel(const float* __restrict__ hcat,
                           const float* __restrict__ W1, const float* __restrict__ b1,
                           const float* __restrict__ W2, const float* __restrict__ b2,
                           float* __restrict__ out)
{
    const int b = blockIdx.x;
    const int tid = threadIdx.x;
    __shared__ float h1[32];
    const float* h = hcat + b * (2 * HID);
    if (tid < 32) {
        float acc = b1[tid];
#pragma unroll
        for (int k = 0; k < 2 * HID; ++k) acc += h[k] * W1[k * 32 + tid];
        h1[tid] = fmaxf(acc, 0.0f);
    }
    __syncthreads();
    if (tid == 0) {
        float acc = b2[0];
#pragma unroll
        for (int m = 0; m < 32; ++m) acc += h1[m] * W2[m];
        out[b] = acc;
    }
}

extern "C" void kernel_launch(void* const* d_in, const int* in_sizes, int n_in,
                              void* d_out, int out_size, void* d_ws, size_t ws_size,
                              hipStream_t stream)
{
    const int*   x   = (const int*)d_in[0];
    const float* emb = (const float*)d_in[1];
    const float* Wf  = (const float*)d_in[2];
    const float* Uf  = (const float*)d_in[3];
    const float* bf  = (const float*)d_in[4];
    const float* Wb  = (const float*)d_in[5];
    const float* Ub  = (const float*)d_in[6];
    const float* bb  = (const float*)d_in[7];
    const float* W1  = (const float*)d_in[8];
    const float* b1  = (const float*)d_in[9];
    const float* W2  = (const float*)d_in[10];
    const float* b2  = (const float*)d_in[11];
    float* out = (float*)d_out;

    // workspace: [xstream 64MB | embbf | mbits | bfrag | hcat]
    u16*    xstream = (u16*)d_ws;                           // 32*1024*128*8 u16
    u16*    embbf   = xstream + (size_t)32 * 1024 * 1024;   // 50001*64 bf16
    uint32* mbits   = (uint32*)(embbf + 3200064);           // 2*512*32 u32
    u16*    bfragp  = (u16*)(mbits + 2 * 512 * 32);         // 16*2*2*3*512 u16
    float*  hcat    = (float*)(bfragp + 98304);             // 512*128 f32

    embbf_kernel<<<dim3((VOCABP1 * EMB + 255) / 256), dim3(256), 0, stream>>>(emb, embbf);
    maskprep_kernel<<<dim3(2 * 512 * 32 / 256), dim3(256), 0, stream>>>(x, mbits);
    bfrag_kernel<<<dim3(16), dim3(256), 0, stream>>>(Uf, Ub, Wf, Wb, bfragp);
    xstream_kernel<<<dim3(32 * 64), dim3(256), 0, stream>>>(x, embbf, xstream);
    lstm_mfma<<<dim3(64), dim3(512), 0, stream>>>(mbits, xstream, bfragp, bf, bb, hcat);
    mlp_kernel<<<dim3(BATCH), dim3(64), 0, stream>>>(hcat, W1, b1, W2, b2, out);
}

// Round 12
// 747.553 us; speedup vs baseline: 1.1791x; 1.1791x over previous
//
#include <hip/hip_runtime.h>

#define T 1024
#define BATCH 512
#define EMB 64
#define HID 64
#define NGATE 256
#define VOCABP1 50001

typedef unsigned int uint32;
typedef unsigned short u16;
typedef __attribute__((ext_vector_type(8))) short short8;   // 8 bf16 = 4 VGPRs
typedef __attribute__((ext_vector_type(4))) float f32x4;    // MFMA C/D
typedef __attribute__((ext_vector_type(4))) float float4v;

#define L2E 1.44269504088896340736f

__device__ __forceinline__ float rcpf(float x) { return __builtin_amdgcn_rcpf(x); }
__device__ __forceinline__ float exp2as(float x) {   // raw v_exp_f32 (= 2^x)
    float r;
    asm("v_exp_f32 %0, %1" : "=v"(r) : "v"(x));
    return r;
}
// gate activations on PRE-SCALED z (weights folded with -log2e / 2log2e):
__device__ __forceinline__ float sigm_pre(float z)  { return rcpf(1.0f + exp2as(z)); }
__device__ __forceinline__ float tanh_pre(float z)  { return fmaf(-2.0f, rcpf(exp2as(z) + 1.0f), 1.0f); }
__device__ __forceinline__ float tanh_c(float c)    { return tanh_pre(c * (2.0f * L2E)); }

__device__ __forceinline__ u16 f2bf(float x) {        // RNE f32->bf16
    uint32 u = __float_as_uint(x);
    u += 0x7fffu + ((u >> 16) & 1u);
    return (u16)(u >> 16);
}
__device__ __forceinline__ float bf2f(u16 h) { return __uint_as_float(((uint32)h) << 16); }

// LDS-only barrier: drains lgkmcnt but leaves global loads in flight.
#define BARRIER_LDS() asm volatile("s_waitcnt lgkmcnt(0)\n\ts_barrier" ::: "memory")

// ---------------------------------------------------------------------------
// Mask bit-words: mbits[d][b][w] bit i = (x_step(d,b,w*32+i) != 0)
// ---------------------------------------------------------------------------
__global__ void maskprep_kernel(const int* __restrict__ x, uint32* __restrict__ mbits)
{
    const int idx  = blockIdx.x * 256 + threadIdx.x;
    const int word = idx & 31;
    const int db   = idx >> 5;
    const int d    = db >> 9;
    const int b    = db & 511;
    const int* src = x + b * T;
    uint32 m = 0;
#pragma unroll 8
    for (int i = 0; i < 32; ++i) {
        const int t = word * 32 + i;
        m |= (src[d ? (T - 1 - t) : t] != 0 ? 1u : 0u) << i;
    }
    mbits[idx] = m;
}

// ---------------------------------------------------------------------------
// A-fragment emb stream (one stream serves both directions; bwd reads chunk
// 1023-s). Reads f32 emb directly (12.8 MB, L2/L3-cacheable), converts to
// bf16 in-flight — the separate embbf kernel is gone.
// ---------------------------------------------------------------------------
__global__ void xstream_kernel(const int* __restrict__ x,
                               const float* __restrict__ emb,
                               u16* __restrict__ xstream)
{
    const int gb    = blockIdx.x >> 6;
    const int stile = blockIdx.x & 63;
    const int tid   = threadIdx.x;
    const int lane  = tid & 63;
    const int half  = tid >> 6;
    const int ks    = half & 1;
    const int sp    = half >> 1;
    const int m     = lane & 15;
    const int qj    = (lane >> 4) * 8;
#pragma unroll
    for (int i = 0; i < 8; ++i) {
        const int s   = stile * 16 + sp * 8 + i;
        const int tok = x[(gb * 16 + m) * T + s];
        const float* er = emb + (size_t)tok * EMB + ks * 32 + qj;
        const float4v a = *(const float4v*)er;
        const float4v b = *(const float4v*)(er + 4);
        short8 v;
        v[0] = (short)f2bf(a[0]); v[1] = (short)f2bf(a[1]);
        v[2] = (short)f2bf(a[2]); v[3] = (short)f2bf(a[3]);
        v[4] = (short)f2bf(b[0]); v[5] = (short)f2bf(b[1]);
        v[6] = (short)f2bf(b[2]); v[7] = (short)f2bf(b[3]);
        *(short8*)(xstream + ((size_t)(gb * 1024 + s) * 128 + ks * 64 + lane) * 8) = v;
    }
}

// ---------------------------------------------------------------------------
// B-fragment prep: var 0 = U-hi, 1 = U-lo, 2 = W-hi. PRE-SCALED: gate cols
// i,f,o are multiplied by -log2e (sigmoid = rcp(1+exp2(z))), gate g by
// +2*log2e (tanh = 1-2*rcp(exp2(z)+1)) — removes per-gate muls from the
// serial epilogue. hi/lo split happens AFTER scaling.
//   idx = ((((d*4+w)*4+g)*2+ks)*3+var)*512 + lane*8 + j
// ---------------------------------------------------------------------------
__global__ void bfrag_kernel(const float* __restrict__ Uf, const float* __restrict__ Ub,
                             const float* __restrict__ Wf, const float* __restrict__ Wb,
                             u16* __restrict__ bfrag)
{
    const int d = blockIdx.x;
    const float* U = d ? Ub : Uf;
    const float* W = d ? Wb : Wf;
    const int tid = threadIdx.x, lane = tid & 63, w = tid >> 6;
#pragma unroll
    for (int g = 0; g < 4; ++g) {
        const float scale = (g == 2) ? (2.0f * L2E) : (-L2E);
#pragma unroll
        for (int ks = 0; ks < 2; ++ks)
#pragma unroll
        for (int j = 0; j < 8; ++j) {
            const int col = g * 64 + 16 * w + (lane & 15);
            const int k   = ks * 32 + (lane >> 4) * 8 + j;
            const float uv = U[k * NGATE + col] * scale;
            const u16 uhi = f2bf(uv);
            const u16 ulo = f2bf(uv - bf2f(uhi));
            const u16 whi = f2bf(W[k * NGATE + col] * scale);
            const size_t base = ((((size_t)(d * 4 + w) * 4 + g) * 2 + ks) * 3) * 512;
            bfrag[base + 0 * 512 + lane * 8 + j] = uhi;
            bfrag[base + 1 * 512 + lane * 8 + j] = ulo;
            bfrag[base + 2 * 512 + lane * 8 + j] = whi;
        }
    }
}

// ---------------------------------------------------------------------------
// MFMA LSTM (R10 structure, best measured: no gather, no exchange).
// 64 blocks x 256 threads; wave w owns units [16w,16w+16) for all 4 gate
// tiles; per-step: x-part MFMAs pre-barrier (register stream ring), one
// lgkm-only barrier, h-part hi/lo MFMAs, epilogue with pre-scaled exp2
// activations. R11 lesson reverted: gate-interleave + scr exchange added
// 25M bank conflicts and no overlap (barrier-locked waves share phase).
// ---------------------------------------------------------------------------
__global__ __launch_bounds__(256, 1)
void lstm_mfma(const uint32* __restrict__ mbits,
               const u16* __restrict__ xstream,
               const u16* __restrict__ bfragp,
               const float* __restrict__ bf, const float* __restrict__ bb,
               float* __restrict__ hcat)
{
    const int tid  = threadIdx.x;
    const int lane = tid & 63;
    const int w    = tid >> 6;          // unit group
    const int col  = lane & 15;
    const int quad = lane >> 4;
    const int d    = blockIdx.x >> 5;
    const int gb   = blockIdx.x & 31;

    const int ucol = 16 * w + col;
    const int KS   = w >> 1;
    const int q2   = (2 * w + (col >> 3)) & 3;

    // B fragments (AGPR-resident, MFMA reads natively)
    short8 BU[4][2][2];   // [g][ks][hi/lo]
    short8 BW[4][2];      // [g][ks]
    {
        const u16* pb = bfragp + (size_t)(d * 4 + w) * 4 * 2 * 3 * 512;
#pragma unroll
        for (int g = 0; g < 4; ++g)
#pragma unroll
        for (int ks = 0; ks < 2; ++ks) {
            BU[g][ks][0] = *(const short8*)&pb[((g * 2 + ks) * 3 + 0) * 512 + lane * 8];
            BU[g][ks][1] = *(const short8*)&pb[((g * 2 + ks) * 3 + 1) * 512 + lane * 8];
            BW[g][ks]    = *(const short8*)&pb[((g * 2 + ks) * 3 + 2) * 512 + lane * 8];
        }
    }
    float biasv[4];
    {
        const float* bias = d ? bb : bf;
#pragma unroll
        for (int g = 0; g < 4; ++g)
            biasv[g] = bias[g * 64 + ucol] * ((g == 2) ? (2.0f * L2E) : (-L2E));
    }

    __shared__ u16 Ahi[2][2][64][8];   // [buf][ks][row][j]  16B rows, b128-aligned
    __shared__ u16 Alo[2][2][64][8];
    {
        u16* f = &Ahi[0][0][0][0];
        for (int i = tid; i < 2 * 2 * 64 * 8; i += 256) f[i] = 0;
        u16* f2 = &Alo[0][0][0][0];
        for (int i = tid; i < 2 * 2 * 64 * 8; i += 256) f2[i] = 0;
    }

    const uint32* mrow[4];
#pragma unroll
    for (int r = 0; r < 4; ++r)
        mrow[r] = mbits + (size_t)(d * 512 + gb * 16 + quad * 4 + r) * 32;
    uint32 mcur[4], mnext[4];
#pragma unroll
    for (int r = 0; r < 4; ++r) { mcur[r] = mrow[r][0]; mnext[r] = mrow[r][1]; }

    const u16* sptr = xstream + (size_t)gb * 1024 * 1024;   // this gb's stream

    // stream ring: ax[phase][ks], warmup steps 0,1
    short8 axr[2][2];
    {
        const int c0 = d ? 1023 : 0;
        const int c1 = d ? 1022 : 1;
        axr[0][0] = *(const short8*)(sptr + (size_t)c0 * 1024 + lane * 8);
        axr[0][1] = *(const short8*)(sptr + (size_t)c0 * 1024 + 512 + lane * 8);
        axr[1][0] = *(const short8*)(sptr + (size_t)c1 * 1024 + lane * 8);
        axr[1][1] = *(const short8*)(sptr + (size_t)c1 * 1024 + 512 + lane * 8);
    }
    __syncthreads();    // once, outside hot loop

    float hv[4] = {0.f, 0.f, 0.f, 0.f};
    float cv[4] = {0.f, 0.f, 0.f, 0.f};

#define STEP(SV, P, PREF)                                                      \
  {                                                                            \
    /* ---- x-part: register-only, before barrier ---- */                      \
    f32x4 acc[4];                                                              \
    _Pragma("unroll")                                                          \
    for (int g = 0; g < 4; ++g) {                                              \
      acc[g][0] = biasv[g]; acc[g][1] = biasv[g];                              \
      acc[g][2] = biasv[g]; acc[g][3] = biasv[g];                              \
      acc[g] = __builtin_amdgcn_mfma_f32_16x16x32_bf16(axr[P][0], BW[g][0], acc[g], 0, 0, 0); \
      acc[g] = __builtin_amdgcn_mfma_f32_16x16x32_bf16(axr[P][1], BW[g][1], acc[g], 0, 0, 0); \
    }                                                                          \
    /* ---- ring refill for step SV+2 (consumed 2 steps later) ---- */         \
    {                                                                          \
      const int cs = ((SV) + 2 <= 1023) ? ((SV) + 2) : 1023;                   \
      const int c2 = d ? (1023 - cs) : cs;                                     \
      const u16* cp = sptr + (size_t)c2 * 1024;                                \
      axr[P][0] = *(const short8*)(cp + lane * 8);                             \
      axr[P][1] = *(const short8*)(cp + 512 + lane * 8);                       \
    }                                                                          \
    if ((PREF) && (((SV) & 31) == 0) && ((SV) > 0)) {   /* mask window */      \
      const int wn = ((SV) >> 5) + 1;                                          \
      const int wc = (wn < 32) ? wn : 31;                                      \
      _Pragma("unroll")                                                        \
      for (int r = 0; r < 4; ++r) { mcur[r] = mnext[r]; mnext[r] = mrow[r][wc]; } \
    }                                                                          \
    BARRIER_LDS();                                                             \
    /* ---- h-part ---- */                                                     \
    const short8 Hh0 = *(const short8*)&Ahi[1 - (P)][0][lane][0];              \
    const short8 Hh1 = *(const short8*)&Ahi[1 - (P)][1][lane][0];              \
    const short8 Hl0 = *(const short8*)&Alo[1 - (P)][0][lane][0];              \
    const short8 Hl1 = *(const short8*)&Alo[1 - (P)][1][lane][0];              \
    _Pragma("unroll")                                                          \
    for (int g = 0; g < 4; ++g) {                                              \
      acc[g] = __builtin_amdgcn_mfma_f32_16x16x32_bf16(Hh0, BU[g][0][0], acc[g], 0, 0, 0); \
      acc[g] = __builtin_amdgcn_mfma_f32_16x16x32_bf16(Hh1, BU[g][1][0], acc[g], 0, 0, 0); \
      acc[g] = __builtin_amdgcn_mfma_f32_16x16x32_bf16(Hh0, BU[g][0][1], acc[g], 0, 0, 0); \
      acc[g] = __builtin_amdgcn_mfma_f32_16x16x32_bf16(Hh1, BU[g][1][1], acc[g], 0, 0, 0); \
      acc[g] = __builtin_amdgcn_mfma_f32_16x16x32_bf16(Hl0, BU[g][0][0], acc[g], 0, 0, 0); \
      acc[g] = __builtin_amdgcn_mfma_f32_16x16x32_bf16(Hl1, BU[g][1][0], acc[g], 0, 0, 0); \
    }                                                                          \
    /* ---- epilogue: pre-scaled exp2 activations ---- */                      \
    _Pragma("unroll")                                                          \
    for (int r = 0; r < 4; ++r) {                                              \
      const float iv = sigm_pre(acc[0][r]);                                    \
      const float fv = sigm_pre(acc[1][r]);                                    \
      const float gv = tanh_pre(acc[2][r]);                                    \
      const float ov = sigm_pre(acc[3][r]);                                    \
      const float cn = fmaf(fv, cv[r], iv * gv);                               \
      const float hn = ov * tanh_c(cn);                                        \
      if ((mcur[r] >> ((SV) & 31)) & 1) { cv[r] = cn; hv[r] = hn; }            \
      const uint32 uh = __float_as_uint(hv[r]);                                \
      const u16 hhi = (u16)(uh >> 16);                 /* trunc: err -> lo */  \
      const u16 hlo = (u16)(__float_as_uint(hv[r] - bf2f(hhi)) >> 16);         \
      Ahi[(P)][KS][q2 * 16 + quad * 4 + r][col & 7] = hhi;                     \
      Alo[(P)][KS][q2 * 16 + quad * 4 + r][col & 7] = hlo;                     \
    }                                                                          \
  }

    for (int s = 0; s < T; s += 2) {
        STEP(s, 0, 1)
        STEP(s + 1, 1, 0)
    }
#undef STEP

#pragma unroll
    for (int r = 0; r < 4; ++r)
        hcat[(size_t)(gb * 16 + quad * 4 + r) * (2 * HID) + d * HID + ucol] = hv[r];
}

// ---------------------------------------------------------------------------
// Tiny MLP head: out[b] = relu(hcat[b] @ W1 + b1) @ W2 + b2
// ---------------------------------------------------------------------------
__global__ void mlp_kernel(const float* __restrict__ hcat,
                           const float* __restrict__ W1, const float* __restrict__ b1,
                           const float* __restrict__ W2, const float* __restrict__ b2,
                           float* __restrict__ out)
{
    const int b = blockIdx.x;
    const int tid = threadIdx.x;
    __shared__ float h1[32];
    const float* h = hcat + b * (2 * HID);
    if (tid < 32) {
        float acc = b1[tid];
#pragma unroll
        for (int k = 0; k < 2 * HID; ++k) acc += h[k] * W1[k * 32 + tid];
        h1[tid] = fmaxf(acc, 0.0f);
    }
    __syncthreads();
    if (tid == 0) {
        float acc = b2[0];
#pragma unroll
        for (int m = 0; m < 32; ++m) acc += h1[m] * W2[m];
        out[b] = acc;
    }
}

extern "C" void kernel_launch(void* const* d_in, const int* in_sizes, int n_in,
                              void* d_out, int out_size, void* d_ws, size_t ws_size,
                              hipStream_t stream)
{
    const int*   x   = (const int*)d_in[0];
    const float* emb = (const float*)d_in[1];
    const float* Wf  = (const float*)d_in[2];
    const float* Uf  = (const float*)d_in[3];
    const float* bf  = (const float*)d_in[4];
    const float* Wb  = (const float*)d_in[5];
    const float* Ub  = (const float*)d_in[6];
    const float* bb  = (const float*)d_in[7];
    const float* W1  = (const float*)d_in[8];
    const float* b1  = (const float*)d_in[9];
    const float* W2  = (const float*)d_in[10];
    const float* b2  = (const float*)d_in[11];
    float* out = (float*)d_out;

    // workspace: [xstream 64MB | mbits | bfrag | hcat]
    u16*    xstream = (u16*)d_ws;                           // 32*1024*128*8 u16
    uint32* mbits   = (uint32*)(xstream + (size_t)32 * 1024 * 1024);  // 2*512*32 u32
    u16*    bfragp  = (u16*)(mbits + 2 * 512 * 32);         // 98304 u16
    float*  hcat    = (float*)(bfragp + 98304);             // 512*128 f32

    maskprep_kernel<<<dim3(2 * 512 * 32 / 256), dim3(256), 0, stream>>>(x, mbits);
    bfrag_kernel<<<dim3(2), dim3(256), 0, stream>>>(Uf, Ub, Wf, Wb, bfragp);
    xstream_kernel<<<dim3(32 * 64), dim3(256), 0, stream>>>(x, emb, xstream);
    lstm_mfma<<<dim3(64), dim3(256), 0, stream>>>(mbits, xstream, bfragp, bf, bb, hcat);
    mlp_kernel<<<dim3(BATCH), dim3(64), 0, stream>>>(hcat, W1, b1, W2, b2, out);
}

// Round 13
// 653.022 us; speedup vs baseline: 1.3497x; 1.1448x over previous
//
#include <hip/hip_runtime.h>

#define T 1024
#define BATCH 512
#define EMB 64
#define HID 64
#define NGATE 256
#define VOCABP1 50001

typedef unsigned int uint32;
typedef unsigned short u16;
typedef __attribute__((ext_vector_type(8))) short short8;   // 8 bf16 = 4 VGPRs
typedef __attribute__((ext_vector_type(4))) float f32x4;    // MFMA C/D
typedef __attribute__((ext_vector_type(4))) float float4v;

#define L2E 1.44269504088896340736f

__device__ __forceinline__ float rcpf(float x) { return __builtin_amdgcn_rcpf(x); }
__device__ __forceinline__ float exp2as(float x) {   // raw v_exp_f32 (= 2^x)
    float r;
    asm("v_exp_f32 %0, %1" : "=v"(r) : "v"(x));
    return r;
}
// gate activations on PRE-SCALED z (weights folded with -log2e / 2log2e):
__device__ __forceinline__ float sigm_pre(float z)  { return rcpf(1.0f + exp2as(z)); }
__device__ __forceinline__ float tanh_pre(float z)  { return fmaf(-2.0f, rcpf(exp2as(z) + 1.0f), 1.0f); }
__device__ __forceinline__ float tanh_c(float c)    { return tanh_pre(c * (2.0f * L2E)); }

__device__ __forceinline__ u16 f2bf(float x) {        // RNE f32->bf16
    uint32 u = __float_as_uint(x);
    u += 0x7fffu + ((u >> 16) & 1u);
    return (u16)(u >> 16);
}
__device__ __forceinline__ float bf2f(u16 h) { return __uint_as_float(((uint32)h) << 16); }

// LDS-only barrier: drains lgkmcnt but leaves global loads in flight.
#define BARRIER_LDS() asm volatile("s_waitcnt lgkmcnt(0)\n\ts_barrier" ::: "memory")
#define WAIT_LDS()    asm volatile("s_waitcnt lgkmcnt(0)" ::: "memory")

// ---------------------------------------------------------------------------
// Mask bit-words: mbits[d][b][w] bit i = (x_step(d,b,w*32+i) != 0)
// ---------------------------------------------------------------------------
__global__ void maskprep_kernel(const int* __restrict__ x, uint32* __restrict__ mbits)
{
    const int idx  = blockIdx.x * 256 + threadIdx.x;
    const int word = idx & 31;
    const int db   = idx >> 5;
    const int d    = db >> 9;
    const int b    = db & 511;
    const int* src = x + b * T;
    uint32 m = 0;
#pragma unroll 8
    for (int i = 0; i < 32; ++i) {
        const int t = word * 32 + i;
        m |= (src[d ? (T - 1 - t) : t] != 0 ? 1u : 0u) << i;
    }
    mbits[idx] = m;
}

// ---------------------------------------------------------------------------
// A-fragment emb stream (one stream per 16-seq group serves both directions
// and all four 4-seq sub-blocks). f32 emb -> bf16 in-flight.
// ---------------------------------------------------------------------------
__global__ void xstream_kernel(const int* __restrict__ x,
                               const float* __restrict__ emb,
                               u16* __restrict__ xstream)
{
    const int gb    = blockIdx.x >> 6;
    const int stile = blockIdx.x & 63;
    const int tid   = threadIdx.x;
    const int lane  = tid & 63;
    const int half  = tid >> 6;
    const int ks    = half & 1;
    const int sp    = half >> 1;
    const int m     = lane & 15;
    const int qj    = (lane >> 4) * 8;
#pragma unroll
    for (int i = 0; i < 8; ++i) {
        const int s   = stile * 16 + sp * 8 + i;
        const int tok = x[(gb * 16 + m) * T + s];
        const float* er = emb + (size_t)tok * EMB + ks * 32 + qj;
        const float4v a = *(const float4v*)er;
        const float4v b = *(const float4v*)(er + 4);
        short8 v;
        v[0] = (short)f2bf(a[0]); v[1] = (short)f2bf(a[1]);
        v[2] = (short)f2bf(a[2]); v[3] = (short)f2bf(a[3]);
        v[4] = (short)f2bf(b[0]); v[5] = (short)f2bf(b[1]);
        v[6] = (short)f2bf(b[2]); v[7] = (short)f2bf(b[3]);
        *(short8*)(xstream + ((size_t)(gb * 1024 + s) * 128 + ks * 64 + lane) * 8) = v;
    }
}

// ---------------------------------------------------------------------------
// B-fragment prep: var 0 = U-hi, 1 = U-lo, 2 = W-hi, PRE-SCALED by -log2e
// (i,f,o) / +2log2e (g). idx = ((((d*4+w)*4+g)*2+ks)*3+var)*512 + lane*8 + j
// ---------------------------------------------------------------------------
__global__ void bfrag_kernel(const float* __restrict__ Uf, const float* __restrict__ Ub,
                             const float* __restrict__ Wf, const float* __restrict__ Wb,
                             u16* __restrict__ bfrag)
{
    const int d = blockIdx.x;
    const float* U = d ? Ub : Uf;
    const float* W = d ? Wb : Wf;
    const int tid = threadIdx.x, lane = tid & 63, w = tid >> 6;
#pragma unroll
    for (int g = 0; g < 4; ++g) {
        const float scale = (g == 2) ? (2.0f * L2E) : (-L2E);
#pragma unroll
        for (int ks = 0; ks < 2; ++ks)
#pragma unroll
        for (int j = 0; j < 8; ++j) {
            const int col = g * 64 + 16 * w + (lane & 15);
            const int k   = ks * 32 + (lane >> 4) * 8 + j;
            const float uv = U[k * NGATE + col] * scale;
            const u16 uhi = f2bf(uv);
            const u16 ulo = f2bf(uv - bf2f(uhi));
            const u16 whi = f2bf(W[k * NGATE + col] * scale);
            const size_t base = ((((size_t)(d * 4 + w) * 4 + g) * 2 + ks) * 3) * 512;
            bfrag[base + 0 * 512 + lane * 8 + j] = uhi;
            bfrag[base + 1 * 512 + lane * 8 + j] = ulo;
            bfrag[base + 2 * 512 + lane * 8 + j] = whi;
        }
    }
}

// ---------------------------------------------------------------------------
// MFMA LSTM v3: 256 blocks x 256 threads — 4 seqs/block (M=4 rows of the
// 16x16 tile; rows for other seqs stay zero). All 256 CUs active; per-CU
// MFMA time unchanged, serial epilogue VALU per block cut 4x. Epilogue is
// redistributed WITHIN each wave: producer quad (quad==sub) writes its 4
// C-rows via 4 conflict-free ds_write_b128; every lane then handles exactly
// one (seq,unit) pair (10 trans vs 40). 8 blocks share one 16-seq xstream;
// blockIdx swizzled so sharers are congruent mod 8 (XCD co-location).
// ---------------------------------------------------------------------------
__global__ __launch_bounds__(256, 1)
void lstm_mfma(const uint32* __restrict__ mbits,
               const u16* __restrict__ xstream,
               const u16* __restrict__ bfragp,
               const float* __restrict__ bf, const float* __restrict__ bb,
               float* __restrict__ hcat)
{
    const int tid  = threadIdx.x;
    const int lane = tid & 63;
    const int w    = tid >> 6;          // unit group: units [16w, 16w+16)
    const int col  = lane & 15;
    const int quad = lane >> 4;
    // swizzled decode: sharers of one gb16 are congruent mod 8 -> same XCD
    const int gb16  = blockIdx.x & 31;
    const int inner = blockIdx.x >> 5;  // 0..7
    const int d     = inner >> 2;
    const int sub   = inner & 3;        // seqs 16*gb16 + 4*sub + [0,4)

    const int ucol = 16 * w + col;
    const int KS   = w >> 1;

    // B fragments (per (d,w), shared across sub-blocks)
    short8 BU[4][2][2];   // [g][ks][hi/lo]
    short8 BW[4][2];      // [g][ks]
    {
        const u16* pb = bfragp + (size_t)(d * 4 + w) * 4 * 2 * 3 * 512;
#pragma unroll
        for (int g = 0; g < 4; ++g)
#pragma unroll
        for (int ks = 0; ks < 2; ++ks) {
            BU[g][ks][0] = *(const short8*)&pb[((g * 2 + ks) * 3 + 0) * 512 + lane * 8];
            BU[g][ks][1] = *(const short8*)&pb[((g * 2 + ks) * 3 + 1) * 512 + lane * 8];
            BW[g][ks]    = *(const short8*)&pb[((g * 2 + ks) * 3 + 2) * 512 + lane * 8];
        }
    }
    float biasv[4];
    {
        const float* bias = d ? bb : bf;
#pragma unroll
        for (int g = 0; g < 4; ++g)
            biasv[g] = bias[g * 64 + ucol] * ((g == 2) ? (2.0f * L2E) : (-L2E));
    }

    __shared__ u16 Ahi[2][2][64][8];     // [buf][ks][row][j] — only our 4 m-rows written
    __shared__ u16 Alo[2][2][64][8];
    __shared__ float scr[8][4][16][4];   // [w][g][col][p] gate exchange, 2-way banks
    {
        u16* f = &Ahi[0][0][0][0];
        for (int i = tid; i < 2 * 2 * 64 * 8; i += 256) f[i] = 0;
        u16* f2 = &Alo[0][0][0][0];
        for (int i = tid; i < 2 * 2 * 64 * 8; i += 256) f2[i] = 0;
    }

    // epilogue identity: this thread owns (seq-local p=quad, unit 16w+col)
    const uint32* mrow = mbits + (size_t)(d * 512 + gb16 * 16 + 4 * sub + quad) * 32;
    uint32 mcur = mrow[0], mnext = mrow[1];
    // h-write target: global m-row = 4*sub + p, A-frag row = q2u*16 + m
    const int q2u  = (2 * w + (col >> 3)) & 3;
    const int hrow = q2u * 16 + 4 * sub + quad;
    const int hj   = col & 7;

    const u16* sptr = xstream + (size_t)gb16 * 1024 * 1024;

    short8 axr[2][2];
    {
        const int c0 = d ? 1023 : 0;
        const int c1 = d ? 1022 : 1;
        axr[0][0] = *(const short8*)(sptr + (size_t)c0 * 1024 + lane * 8);
        axr[0][1] = *(const short8*)(sptr + (size_t)c0 * 1024 + 512 + lane * 8);
        axr[1][0] = *(const short8*)(sptr + (size_t)c1 * 1024 + lane * 8);
        axr[1][1] = *(const short8*)(sptr + (size_t)c1 * 1024 + 512 + lane * 8);
    }
    __syncthreads();    // once, outside hot loop

    float hv = 0.f, cv = 0.f;

#define STEP(SV, P, PREF)                                                      \
  {                                                                            \
    /* ---- x-part: register-only, before barrier ---- */                      \
    f32x4 acc[4];                                                              \
    _Pragma("unroll")                                                          \
    for (int g = 0; g < 4; ++g) {                                              \
      acc[g][0] = biasv[g]; acc[g][1] = biasv[g];                              \
      acc[g][2] = biasv[g]; acc[g][3] = biasv[g];                              \
      acc[g] = __builtin_amdgcn_mfma_f32_16x16x32_bf16(axr[P][0], BW[g][0], acc[g], 0, 0, 0); \
      acc[g] = __builtin_amdgcn_mfma_f32_16x16x32_bf16(axr[P][1], BW[g][1], acc[g], 0, 0, 0); \
    }                                                                          \
    /* ---- ring refill for step SV+2 ---- */                                  \
    {                                                                          \
      const int cs = ((SV) + 2 <= 1023) ? ((SV) + 2) : 1023;                   \
      const int c2 = d ? (1023 - cs) : cs;                                     \
      const u16* cp = sptr + (size_t)c2 * 1024;                                \
      axr[P][0] = *(const short8*)(cp + lane * 8);                             \
      axr[P][1] = *(const short8*)(cp + 512 + lane * 8);                       \
    }                                                                          \
    if ((PREF) && (((SV) & 31) == 0) && ((SV) > 0)) {   /* mask window */      \
      const int wn = ((SV) >> 5) + 1;                                          \
      const int wc = (wn < 32) ? wn : 31;                                      \
      mcur = mnext; mnext = mrow[wc];                                          \
    }                                                                          \
    BARRIER_LDS();                                                             \
    /* ---- h-part ---- */                                                     \
    const short8 Hh0 = *(const short8*)&Ahi[1 - (P)][0][lane][0];              \
    const short8 Hh1 = *(const short8*)&Ahi[1 - (P)][1][lane][0];              \
    const short8 Hl0 = *(const short8*)&Alo[1 - (P)][0][lane][0];              \
    const short8 Hl1 = *(const short8*)&Alo[1 - (P)][1][lane][0];              \
    _Pragma("unroll")                                                          \
    for (int g = 0; g < 4; ++g) {                                              \
      acc[g] = __builtin_amdgcn_mfma_f32_16x16x32_bf16(Hh0, BU[g][0][0], acc[g], 0, 0, 0); \
      acc[g] = __builtin_amdgcn_mfma_f32_16x16x32_bf16(Hh1, BU[g][1][0], acc[g], 0, 0, 0); \
      acc[g] = __builtin_amdgcn_mfma_f32_16x16x32_bf16(Hh0, BU[g][0][1], acc[g], 0, 0, 0); \
      acc[g] = __builtin_amdgcn_mfma_f32_16x16x32_bf16(Hh1, BU[g][1][1], acc[g], 0, 0, 0); \
      acc[g] = __builtin_amdgcn_mfma_f32_16x16x32_bf16(Hl0, BU[g][0][0], acc[g], 0, 0, 0); \
      acc[g] = __builtin_amdgcn_mfma_f32_16x16x32_bf16(Hl1, BU[g][1][0], acc[g], 0, 0, 0); \
    }                                                                          \
    /* ---- intra-wave gate exchange (producer quad == sub) ---- */            \
    if (quad == sub) {                                                         \
      _Pragma("unroll")                                                        \
      for (int g = 0; g < 4; ++g)                                              \
        *(f32x4*)&scr[w][g][col][0] = acc[g];                                  \
    }                                                                          \
    WAIT_LDS();                                                                \
    const float gi = scr[w][0][col][quad];                                     \
    const float gf = scr[w][1][col][quad];                                     \
    const float gg = scr[w][2][col][quad];                                     \
    const float go = scr[w][3][col][quad];                                     \
    /* ---- epilogue: ONE (seq,unit) pair per thread ---- */                   \
    {                                                                          \
      const float iv = sigm_pre(gi);                                           \
      const float fv = sigm_pre(gf);                                           \
      const float gv = tanh_pre(gg);                                           \
      const float ov = sigm_pre(go);                                           \
      const float cn = fmaf(fv, cv, iv * gv);                                  \
      const float hn = ov * tanh_c(cn);                                        \
      if ((mcur >> ((SV) & 31)) & 1) { cv = cn; hv = hn; }                     \
      const uint32 uh = __float_as_uint(hv);                                   \
      const u16 hhi = (u16)(uh >> 16);                                         \
      const u16 hlo = (u16)(__float_as_uint(hv - bf2f(hhi)) >> 16);            \
      Ahi[(P)][KS][hrow][hj] = hhi;                                            \
      Alo[(P)][KS][hrow][hj] = hlo;                                            \
    }                                                                          \
  }

    for (int s = 0; s < T; s += 2) {
        STEP(s, 0, 1)
        STEP(s + 1, 1, 0)
    }
#undef STEP

    hcat[(size_t)(gb16 * 16 + 4 * sub + quad) * (2 * HID) + d * HID + ucol] = hv;
}

// ---------------------------------------------------------------------------
// Tiny MLP head: out[b] = relu(hcat[b] @ W1 + b1) @ W2 + b2
// ---------------------------------------------------------------------------
__global__ void mlp_kernel(const float* __restrict__ hcat,
                           const float* __restrict__ W1, const float* __restrict__ b1,
                           const float* __restrict__ W2, const float* __restrict__ b2,
                           float* __restrict__ out)
{
    const int b = blockIdx.x;
    const int tid = threadIdx.x;
    __shared__ float h1[32];
    const float* h = hcat + b * (2 * HID);
    if (tid < 32) {
        float acc = b1[tid];
#pragma unroll
        for (int k = 0; k < 2 * HID; ++k) acc += h[k] * W1[k * 32 + tid];
        h1[tid] = fmaxf(acc, 0.0f);
    }
    __syncthreads();
    if (tid == 0) {
        float acc = b2[0];
#pragma unroll
        for (int m = 0; m < 32; ++m) acc += h1[m] * W2[m];
        out[b] = acc;
    }
}

extern "C" void kernel_launch(void* const* d_in, const int* in_sizes, int n_in,
                              void* d_out, int out_size, void* d_ws, size_t ws_size,
                              hipStream_t stream)
{
    const int*   x   = (const int*)d_in[0];
    const float* emb = (const float*)d_in[1];
    const float* Wf  = (const float*)d_in[2];
    const float* Uf  = (const float*)d_in[3];
    const float* bf  = (const float*)d_in[4];
    const float* Wb  = (const float*)d_in[5];
    const float* Ub  = (const float*)d_in[6];
    const float* bb  = (const float*)d_in[7];
    const float* W1  = (const float*)d_in[8];
    const float* b1  = (const float*)d_in[9];
    const float* W2  = (const float*)d_in[10];
    const float* b2  = (const float*)d_in[11];
    float* out = (float*)d_out;

    // workspace: [xstream 64MB | mbits | bfrag | hcat]
    u16*    xstream = (u16*)d_ws;                           // 32*1024*128*8 u16
    uint32* mbits   = (uint32*)(xstream + (size_t)32 * 1024 * 1024);  // 2*512*32 u32
    u16*    bfragp  = (u16*)(mbits + 2 * 512 * 32);         // 98304 u16
    float*  hcat    = (float*)(bfragp + 98304);             // 512*128 f32

    maskprep_kernel<<<dim3(2 * 512 * 32 / 256), dim3(256), 0, stream>>>(x, mbits);
    bfrag_kernel<<<dim3(2), dim3(256), 0, stream>>>(Uf, Ub, Wf, Wb, bfragp);
    xstream_kernel<<<dim3(32 * 64), dim3(256), 0, stream>>>(x, emb, xstream);
    lstm_mfma<<<dim3(256), dim3(256), 0, stream>>>(mbits, xstream, bfragp, bf, bb, hcat);
    mlp_kernel<<<dim3(BATCH), dim3(64), 0, stream>>>(hcat, W1, b1, W2, b2, out);
}